// Round 2
// baseline (639.578 us; speedup 1.0000x reference)
//
#include <hip/hip_runtime.h>
#include <hip/hip_bf16.h>

#define NB 32
#define NS 2048
#define NDD 1024
#define NDE 1024
#define NDA 1024
#define NEGV (-1000000000.0f)

typedef __attribute__((ext_vector_type(8))) __bf16 bf16x8;
typedef __attribute__((ext_vector_type(4))) float f32x4;
typedef __attribute__((ext_vector_type(16))) float f32x16;

__device__ __forceinline__ float fast_tanh(float x) {
    x = fminf(10.0f, fmaxf(-10.0f, x));
    float e = __expf(2.0f * x);
    return __fdividef(e - 1.0f, e + 1.0f);
}

// ---------------- We (f32) -> bf16 conversion ----------------
__global__ void prep_we(const float* __restrict__ Wc, __bf16* __restrict__ We) {
    int f = blockIdx.x * 256 + threadIdx.x;       // float4 index, total 1024*1024/4
    int a  = f >> 8;                              // 256 float4 per row
    int k4 = f & 255;
    float4 v = *reinterpret_cast<const float4*>(Wc + (size_t)a * (NDD + NDE) + NDD + k4 * 4);
    union { __bf16 h[4]; uint2 u; } pk;
    pk.h[0] = (__bf16)v.x; pk.h[1] = (__bf16)v.y;
    pk.h[2] = (__bf16)v.z; pk.h[3] = (__bf16)v.w;
    *reinterpret_cast<uint2*>(We + (size_t)a * NDE + k4 * 4) = pk.u;
}

// ---------------- q_proj = query @ Wq^T (f32, exact) ----------------
__global__ void qproj_kernel(const float* __restrict__ q, const float* __restrict__ Wc,
                             float* __restrict__ qp) {
    __shared__ float qs[NDD];
    int b = blockIdx.y;
    int a = blockIdx.x * 256 + threadIdx.x;
    float4 qv = *reinterpret_cast<const float4*>(q + (size_t)b * NDD + threadIdx.x * 4);
    *reinterpret_cast<float4*>(qs + threadIdx.x * 4) = qv;
    __syncthreads();
    const float* wrow = Wc + (size_t)a * (NDD + NDE);
    float acc = 0.f;
#pragma unroll 4
    for (int k4 = 0; k4 < 256; ++k4) {
        float4 w = *reinterpret_cast<const float4*>(wrow + k4 * 4);
        acc += qs[k4*4+0] * w.x + qs[k4*4+1] * w.y + qs[k4*4+2] * w.z + qs[k4*4+3] * w.w;
    }
    qp[(size_t)b * NDA + a] = acc;
}

// ---------------- fused e_proj GEMM + tanh + V-dot -> scores ----------------
// No LDS staging, no main-loop barriers. Block = 64 rows x 1024 a, 8 waves.
// Wave w: rows [row0, row0+64) x a-range [w*128, w*128+128), 32x32x16 MFMA.
// A-frags converted f32->bf16 inline from E; B-frags read bf16 We from L2.
__global__ __launch_bounds__(512, 2) void score_kernel(
    const float* __restrict__ E, const __bf16* __restrict__ We,
    const float* __restrict__ qp, const float* __restrict__ Vv,
    float* __restrict__ scores) {
    __shared__ float score_lds[64];

    const int tid  = threadIdx.x;
    const int lane = tid & 63;
    const int wave = tid >> 6;
    const int row0 = blockIdx.x * 64;
    const int b    = blockIdx.x >> 5;       // row0 / 2048
    const int a0   = wave * 128;
    const int h    = lane >> 5;             // k-half within frag

    if (tid < 64) score_lds[tid] = 0.f;
    __syncthreads();

    f32x16 acc[2][4];
#pragma unroll
    for (int mf = 0; mf < 2; ++mf)
#pragma unroll
        for (int nf = 0; nf < 4; ++nf)
#pragma unroll
            for (int r = 0; r < 16; ++r) acc[mf][nf][r] = 0.f;

    // per-lane base pointers
    const float*  arow = E  + (size_t)(row0 + (lane & 31)) * NDE + h * 8;
    const __bf16* brow = We + (size_t)(a0   + (lane & 31)) * NDE + h * 8;

    // K loop: 64 slices of K=16, unrolled by 2 so each 64B line is consumed adjacently
    for (int c = 0; c < 64; c += 2) {
        bf16x8 af0[2], af1[2];
#pragma unroll
        for (int mf = 0; mf < 2; ++mf) {
            const float* p = arow + (size_t)mf * 32 * NDE + c * 16;
            float4 x0 = *reinterpret_cast<const float4*>(p);
            float4 y0 = *reinterpret_cast<const float4*>(p + 4);
            float4 x1 = *reinterpret_cast<const float4*>(p + 16);
            float4 y1 = *reinterpret_cast<const float4*>(p + 20);
            af0[mf][0] = (__bf16)x0.x; af0[mf][1] = (__bf16)x0.y;
            af0[mf][2] = (__bf16)x0.z; af0[mf][3] = (__bf16)x0.w;
            af0[mf][4] = (__bf16)y0.x; af0[mf][5] = (__bf16)y0.y;
            af0[mf][6] = (__bf16)y0.z; af0[mf][7] = (__bf16)y0.w;
            af1[mf][0] = (__bf16)x1.x; af1[mf][1] = (__bf16)x1.y;
            af1[mf][2] = (__bf16)x1.z; af1[mf][3] = (__bf16)x1.w;
            af1[mf][4] = (__bf16)y1.x; af1[mf][5] = (__bf16)y1.y;
            af1[mf][6] = (__bf16)y1.z; af1[mf][7] = (__bf16)y1.w;
        }
        bf16x8 bf0[4], bf1[4];
#pragma unroll
        for (int nf = 0; nf < 4; ++nf) {
            const __bf16* p = brow + (size_t)nf * 32 * NDE + c * 16;
            bf0[nf] = *reinterpret_cast<const bf16x8*>(p);
            bf1[nf] = *reinterpret_cast<const bf16x8*>(p + 16);
        }
#pragma unroll
        for (int mf = 0; mf < 2; ++mf)
#pragma unroll
            for (int nf = 0; nf < 4; ++nf)
                acc[mf][nf] = __builtin_amdgcn_mfma_f32_32x32x16_bf16(
                    af0[mf], bf0[nf], acc[mf][nf], 0, 0, 0);
#pragma unroll
        for (int mf = 0; mf < 2; ++mf)
#pragma unroll
            for (int nf = 0; nf < 4; ++nf)
                acc[mf][nf] = __builtin_amdgcn_mfma_f32_32x32x16_bf16(
                    af1[mf], bf1[nf], acc[mf][nf], 0, 0, 0);
    }

    // ---- epilogue: tanh(qp + e_proj) * V, reduce over a ----
    const int colbase = a0 + (lane & 31);
#pragma unroll
    for (int mf = 0; mf < 2; ++mf) {
        float ps[16];
#pragma unroll
        for (int r = 0; r < 16; ++r) ps[r] = 0.f;
#pragma unroll
        for (int nf = 0; nf < 4; ++nf) {
            int col = colbase + nf * 32;
            float qv = qp[(size_t)b * NDA + col];
            float vv = Vv[col];
#pragma unroll
            for (int r = 0; r < 16; ++r)
                ps[r] += fast_tanh(qv + acc[mf][nf][r]) * vv;
        }
        // C/D layout 32x32: row = (r&3) + 8*(r>>2) + 4*h, col = lane&31.
        // reduce over the 32 lanes (col dim) holding the same row.
#pragma unroll
        for (int r = 0; r < 16; ++r) {
            float v = ps[r];
            v += __shfl_xor(v, 1);
            v += __shfl_xor(v, 2);
            v += __shfl_xor(v, 4);
            v += __shfl_xor(v, 8);
            v += __shfl_xor(v, 16);
            if ((lane & 31) == 0) {
                int row = mf * 32 + (r & 3) + 8 * (r >> 2) + 4 * h;
                atomicAdd(&score_lds[row], v);
            }
        }
    }
    __syncthreads();
    if (tid < 64) scores[row0 + tid] = score_lds[tid];
}

// ---------------- masked softmax over s, per b ----------------
__global__ void softmax_kernel(const float* __restrict__ scores, const int* __restrict__ mask,
                               float* __restrict__ wout) {
    int b = blockIdx.x;
    const float* srow = scores + (size_t)b * NS;
    const int* mrow = mask + (size_t)b * NS;
    float v[8];
    float lmax = -INFINITY;
#pragma unroll
    for (int j = 0; j < 8; ++j) {
        int s = threadIdx.x + 256 * j;
        v[j] = (mrow[s] == 0) ? NEGV : srow[s];
        lmax = fmaxf(lmax, v[j]);
    }
#pragma unroll
    for (int m = 1; m <= 32; m <<= 1) lmax = fmaxf(lmax, __shfl_xor(lmax, m));
    __shared__ float redm[4], reds[4];
    if ((threadIdx.x & 63) == 0) redm[threadIdx.x >> 6] = lmax;
    __syncthreads();
    float bmax = fmaxf(fmaxf(redm[0], redm[1]), fmaxf(redm[2], redm[3]));
    float lsum = 0.f;
#pragma unroll
    for (int j = 0; j < 8; ++j) { v[j] = __expf(v[j] - bmax); lsum += v[j]; }
#pragma unroll
    for (int m = 1; m <= 32; m <<= 1) lsum += __shfl_xor(lsum, m);
    if ((threadIdx.x & 63) == 0) reds[threadIdx.x >> 6] = lsum;
    __syncthreads();
    float inv = __fdividef(1.0f, reds[0] + reds[1] + reds[2] + reds[3]);
#pragma unroll
    for (int j = 0; j < 8; ++j) wout[(size_t)b * NS + threadIdx.x + 256 * j] = v[j] * inv;
}

// ---------------- context = w @ E ----------------
// grid 256: b = bx>>3, d-chunk (128 d) = bx&7.  256 thr: 64 float2-lanes x 4-way s-split.
__global__ void context_kernel(const float* __restrict__ E, const float* __restrict__ w,
                               float* __restrict__ ctx) {
    int b  = blockIdx.x >> 3;
    int dc = blockIdx.x & 7;
    int d2 = dc * 64 + (threadIdx.x & 63);      // float2 index within row (512 per row)
    int s0 = (threadIdx.x >> 6) * 512;
    const float2* Eb = reinterpret_cast<const float2*>(E) + (size_t)b * NS * (NDE / 2);
    const float* wb = w + (size_t)b * NS;
    float ax = 0.f, ay = 0.f;
#pragma unroll 8
    for (int s = s0; s < s0 + 512; ++s) {
        float ws = wb[s];
        float2 e = Eb[(size_t)s * (NDE / 2) + d2];
        ax = fmaf(ws, e.x, ax);
        ay = fmaf(ws, e.y, ay);
    }
    __shared__ float2 part[256];
    part[threadIdx.x] = make_float2(ax, ay);
    __syncthreads();
    if (threadIdx.x < 64) {
        float2 p0 = part[threadIdx.x], p1 = part[threadIdx.x + 64];
        float2 p2 = part[threadIdx.x + 128], p3 = part[threadIdx.x + 192];
        float2 r = make_float2(p0.x + p1.x + p2.x + p3.x, p0.y + p1.y + p2.y + p3.y);
        reinterpret_cast<float2*>(ctx + (size_t)b * NDD + dc * 128)[threadIdx.x] = r;
    }
}

extern "C" void kernel_launch(void* const* d_in, const int* in_sizes, int n_in,
                              void* d_out, int out_size, void* d_ws, size_t ws_size,
                              hipStream_t stream) {
    const float* query = (const float*)d_in[0];
    const float* enc   = (const float*)d_in[1];
    const int*   mask  = (const int*)d_in[2];
    const float* Wc    = (const float*)d_in[3];
    const float* V     = (const float*)d_in[4];

    float* out = (float*)d_out;
    float* ctx = out;                       // (32,1024)
    float* wts = out + NB * NDD;            // (32,2048)

    char* ws = (char*)d_ws;
    __bf16* We    = (__bf16*)ws;                                         // 2 MB
    float*  qp    = (float*)(ws + (size_t)NDA * NDE * 2);                // 128 KB
    float*  scores= (float*)(ws + (size_t)NDA * NDE * 2 + NB * NDA * 4); // 256 KB

    hipLaunchKernelGGL(prep_we,        dim3(1024),      dim3(256), 0, stream, Wc, We);
    hipLaunchKernelGGL(qproj_kernel,   dim3(4, NB),     dim3(256), 0, stream, query, Wc, qp);
    hipLaunchKernelGGL(score_kernel,   dim3(1024),      dim3(512), 0, stream, enc, We, qp, V, scores);
    hipLaunchKernelGGL(softmax_kernel, dim3(NB),        dim3(256), 0, stream, scores, mask, wts);
    hipLaunchKernelGGL(context_kernel, dim3(256),       dim3(256), 0, stream, enc, wts, ctx);
}

// Round 3
// 392.075 us; speedup vs baseline: 1.6313x; 1.6313x over previous
//
#include <hip/hip_runtime.h>
#include <hip/hip_bf16.h>

#define NB 32
#define NS 2048
#define NDD 1024
#define NDE 1024
#define NDA 1024
#define NEGV (-1000000000.0f)

typedef __attribute__((ext_vector_type(8))) __bf16 bf16x8;
typedef __attribute__((ext_vector_type(4))) float f32x4;

__device__ __forceinline__ float fast_tanh(float x) {
    x = fminf(10.0f, fmaxf(-10.0f, x));
    float e = __expf(2.0f * x);
    return __fdividef(e - 1.0f, e + 1.0f);
}

// ---------------- We (f32) -> bf16 conversion ----------------
__global__ void prep_we(const float* __restrict__ Wc, __bf16* __restrict__ We) {
    int f = blockIdx.x * 256 + threadIdx.x;       // float4 index, total 1024*1024/4
    int a  = f >> 8;
    int k4 = f & 255;
    float4 v = *reinterpret_cast<const float4*>(Wc + (size_t)a * (NDD + NDE) + NDD + k4 * 4);
    union { __bf16 h[4]; uint2 u; } pk;
    pk.h[0] = (__bf16)v.x; pk.h[1] = (__bf16)v.y;
    pk.h[2] = (__bf16)v.z; pk.h[3] = (__bf16)v.w;
    *reinterpret_cast<uint2*>(We + (size_t)a * NDE + k4 * 4) = pk.u;
}

// ---------------- q_proj = query @ Wq^T (f32, exact) ----------------
__global__ void qproj_kernel(const float* __restrict__ q, const float* __restrict__ Wc,
                             float* __restrict__ qp) {
    __shared__ float qs[NDD];
    int b = blockIdx.y;
    int a = blockIdx.x * 256 + threadIdx.x;
    float4 qv = *reinterpret_cast<const float4*>(q + (size_t)b * NDD + threadIdx.x * 4);
    *reinterpret_cast<float4*>(qs + threadIdx.x * 4) = qv;
    __syncthreads();
    const float* wrow = Wc + (size_t)a * (NDD + NDE);
    float acc = 0.f;
#pragma unroll 4
    for (int k4 = 0; k4 < 256; ++k4) {
        float4 w = *reinterpret_cast<const float4*>(wrow + k4 * 4);
        acc += qs[k4*4+0] * w.x + qs[k4*4+1] * w.y + qs[k4*4+2] * w.z + qs[k4*4+3] * w.w;
    }
    qp[(size_t)b * NDA + a] = acc;
}

// ---------------- fused e_proj GEMM + tanh + V-dot -> partial scores ----------------
// m97-style: 128x128 tile, BK=32, 256 thr / 4 waves (2x2), double-buffered LDS,
// global_load_lds w16 staging. A staged as f32 (slot-swizzled source), converted
// to bf16 at frag read. B = pre-converted bf16 We (4-slot swizzle).
// Block (m,n): rows m*128..+128, cols n*128..+128. Writes scores_p[n][row].
__global__ __launch_bounds__(256) void score_kernel(
    const float* __restrict__ E, const __bf16* __restrict__ We,
    const float* __restrict__ qp, const float* __restrict__ Vv,
    float* __restrict__ scores_p) {
    __shared__ __align__(16) float  As[2][128 * 32];   // 16 KB each (f32, swizzled)
    __shared__ __align__(16) __bf16 Bs[2][128 * 32];   // 8 KB each
    __shared__ float ps_lds[128][2];

    const int tid    = threadIdx.x;
    const int lane   = tid & 63;
    const int lane15 = lane & 15;
    const int h      = lane >> 4;          // 0..3, k-quarter
    const int wid    = tid >> 6;
    const int wr     = wid >> 1;           // 0..1 row half
    const int wc     = wid & 1;            // 0..1 col half

    // XCD-chunked swizzle: xcd gets contiguous m-range, n fastest.
    const int bid = blockIdx.x;
    const int xcd = bid & 7;
    const int j   = bid >> 3;
    const int m   = xcd * 64 + (j >> 3);   // 0..511
    const int n   = j & 7;                 // 0..7
    const int row0  = m * 128;
    const int ncol0 = n * 128;
    const int b     = m >> 4;

    f32x4 acc[4][4];
#pragma unroll
    for (int mi = 0; mi < 4; ++mi)
#pragma unroll
        for (int ni = 0; ni < 4; ++ni)
            acc[mi][ni] = (f32x4){0.f, 0.f, 0.f, 0.f};

    const int wbyte = (tid >> 6) * 1024;   // wave-uniform LDS sub-base

#define STAGE(buf, kc)                                                                 \
    {                                                                                  \
        _Pragma("unroll")                                                              \
        for (int i = 0; i < 4; ++i) {                                                  \
            int ib = i * 4096 + tid * 16;                                              \
            int r = ib >> 7;                                                           \
            int sl = (ib >> 4) & 7;                                                    \
            int sg = sl ^ (r & 7);                                                     \
            const float* g = E + (size_t)(row0 + r) * NDE + (kc) + sg * 4;             \
            __builtin_amdgcn_global_load_lds(                                          \
                (const __attribute__((address_space(1))) unsigned*)g,                  \
                (__attribute__((address_space(3))) unsigned*)((char*)&As[buf][0] + i * 4096 + wbyte), \
                16, 0, 0);                                                             \
        }                                                                              \
        _Pragma("unroll")                                                              \
        for (int i = 0; i < 2; ++i) {                                                  \
            int ib = i * 4096 + tid * 16;                                              \
            int r = ib >> 6;                                                           \
            int sl = (ib >> 4) & 3;                                                    \
            int sg = sl ^ (r & 3);                                                     \
            const __bf16* g = We + (size_t)(ncol0 + r) * NDE + (kc) + sg * 8;          \
            __builtin_amdgcn_global_load_lds(                                          \
                (const __attribute__((address_space(1))) unsigned*)g,                  \
                (__attribute__((address_space(3))) unsigned*)((char*)&Bs[buf][0] + i * 4096 + wbyte), \
                16, 0, 0);                                                             \
        }                                                                              \
    }

    STAGE(0, 0)
    __syncthreads();

    for (int it = 0; it < 32; ++it) {
        const int cur = it & 1;
        if (it < 31) STAGE(cur ^ 1, (it + 1) * 32)

        const char* Ab = (const char*)&As[cur][0];
        const char* Bb = (const char*)&Bs[cur][0];
        bf16x8 bfr[4];
#pragma unroll
        for (int ni = 0; ni < 4; ++ni) {
            int cr = wc * 64 + ni * 16 + lane15;
            bfr[ni] = *reinterpret_cast<const bf16x8*>(Bb + cr * 64 + ((h ^ (cr & 3)) * 16));
        }
#pragma unroll
        for (int mi = 0; mi < 4; ++mi) {
            int r = wr * 64 + mi * 16 + lane15;
            int s0 = (2 * h) ^ (r & 7), s1 = (2 * h + 1) ^ (r & 7);
            f32x4 x = *reinterpret_cast<const f32x4*>(Ab + r * 128 + s0 * 16);
            f32x4 y = *reinterpret_cast<const f32x4*>(Ab + r * 128 + s1 * 16);
            bf16x8 a;
            a[0] = (__bf16)x[0]; a[1] = (__bf16)x[1]; a[2] = (__bf16)x[2]; a[3] = (__bf16)x[3];
            a[4] = (__bf16)y[0]; a[5] = (__bf16)y[1]; a[6] = (__bf16)y[2]; a[7] = (__bf16)y[3];
#pragma unroll
            for (int ni = 0; ni < 4; ++ni)
                acc[mi][ni] = __builtin_amdgcn_mfma_f32_16x16x32_bf16(a, bfr[ni], acc[mi][ni], 0, 0, 0);
        }
        __syncthreads();
    }

    // ---- epilogue: tanh(qp + e_proj) * V, reduce over cols ----
    float qv[4], vv[4];
#pragma unroll
    for (int ni = 0; ni < 4; ++ni) {
        int col = ncol0 + wc * 64 + ni * 16 + lane15;
        qv[ni] = qp[(size_t)b * NDA + col];
        vv[ni] = Vv[col];
    }
#pragma unroll
    for (int mi = 0; mi < 4; ++mi)
#pragma unroll
        for (int jj = 0; jj < 4; ++jj) {
            float s = 0.f;
#pragma unroll
            for (int ni = 0; ni < 4; ++ni)
                s += fast_tanh(qv[ni] + acc[mi][ni][jj]) * vv[ni];
            s += __shfl_xor(s, 1);
            s += __shfl_xor(s, 2);
            s += __shfl_xor(s, 4);
            s += __shfl_xor(s, 8);
            if (lane15 == 0)
                ps_lds[wr * 64 + mi * 16 + h * 4 + jj][wc] = s;
        }
    __syncthreads();
    if (tid < 128)
        scores_p[(size_t)n * (NB * NS) + row0 + tid] = ps_lds[tid][0] + ps_lds[tid][1];
}

// ---------------- masked softmax over s (sums 8 partials), per b ----------------
__global__ void softmax_kernel(const float* __restrict__ sp, const int* __restrict__ mask,
                               float* __restrict__ wout) {
    int b = blockIdx.x;
    const int* mrow = mask + (size_t)b * NS;
    float v[8];
    float lmax = -INFINITY;
#pragma unroll
    for (int jj = 0; jj < 8; ++jj) {
        int s = threadIdx.x + 256 * jj;
        float sc = 0.f;
#pragma unroll
        for (int nn = 0; nn < 8; ++nn) sc += sp[(size_t)nn * (NB * NS) + b * NS + s];
        v[jj] = (mrow[s] == 0) ? NEGV : sc;
        lmax = fmaxf(lmax, v[jj]);
    }
#pragma unroll
    for (int mm = 1; mm <= 32; mm <<= 1) lmax = fmaxf(lmax, __shfl_xor(lmax, mm));
    __shared__ float redm[4], reds[4];
    if ((threadIdx.x & 63) == 0) redm[threadIdx.x >> 6] = lmax;
    __syncthreads();
    float bmax = fmaxf(fmaxf(redm[0], redm[1]), fmaxf(redm[2], redm[3]));
    float lsum = 0.f;
#pragma unroll
    for (int jj = 0; jj < 8; ++jj) { v[jj] = __expf(v[jj] - bmax); lsum += v[jj]; }
#pragma unroll
    for (int mm = 1; mm <= 32; mm <<= 1) lsum += __shfl_xor(lsum, mm);
    if ((threadIdx.x & 63) == 0) reds[threadIdx.x >> 6] = lsum;
    __syncthreads();
    float inv = __fdividef(1.0f, reds[0] + reds[1] + reds[2] + reds[3]);
#pragma unroll
    for (int jj = 0; jj < 8; ++jj) wout[(size_t)b * NS + threadIdx.x + 256 * jj] = v[jj] * inv;
}

// ---------------- context = w @ E ----------------
__global__ void context_kernel(const float* __restrict__ E, const float* __restrict__ w,
                               float* __restrict__ ctx) {
    int b  = blockIdx.x >> 3;
    int dc = blockIdx.x & 7;
    int d2 = dc * 64 + (threadIdx.x & 63);
    int s0 = (threadIdx.x >> 6) * 512;
    const float2* Eb = reinterpret_cast<const float2*>(E) + (size_t)b * NS * (NDE / 2);
    const float* wb = w + (size_t)b * NS;
    float ax = 0.f, ay = 0.f;
#pragma unroll 8
    for (int s = s0; s < s0 + 512; ++s) {
        float ws = wb[s];
        float2 e = Eb[(size_t)s * (NDE / 2) + d2];
        ax = fmaf(ws, e.x, ax);
        ay = fmaf(ws, e.y, ay);
    }
    __shared__ float2 part[256];
    part[threadIdx.x] = make_float2(ax, ay);
    __syncthreads();
    if (threadIdx.x < 64) {
        float2 p0 = part[threadIdx.x], p1 = part[threadIdx.x + 64];
        float2 p2 = part[threadIdx.x + 128], p3 = part[threadIdx.x + 192];
        float2 r = make_float2(p0.x + p1.x + p2.x + p3.x, p0.y + p1.y + p2.y + p3.y);
        reinterpret_cast<float2*>(ctx + (size_t)b * NDD + dc * 128)[threadIdx.x] = r;
    }
}

extern "C" void kernel_launch(void* const* d_in, const int* in_sizes, int n_in,
                              void* d_out, int out_size, void* d_ws, size_t ws_size,
                              hipStream_t stream) {
    const float* query = (const float*)d_in[0];
    const float* enc   = (const float*)d_in[1];
    const int*   mask  = (const int*)d_in[2];
    const float* Wc    = (const float*)d_in[3];
    const float* V     = (const float*)d_in[4];

    float* out = (float*)d_out;
    float* ctx = out;                       // (32,1024)
    float* wts = out + NB * NDD;            // (32,2048)

    char* ws = (char*)d_ws;
    __bf16* We     = (__bf16*)ws;                                          // 2 MB
    float*  qp     = (float*)(ws + (size_t)NDA * NDE * 2);                 // 128 KB
    float*  sp     = (float*)(ws + (size_t)NDA * NDE * 2 + NB * NDA * 4);  // 2 MB (8 partials)

    hipLaunchKernelGGL(prep_we,        dim3(1024),  dim3(256), 0, stream, Wc, We);
    hipLaunchKernelGGL(qproj_kernel,   dim3(4, NB), dim3(256), 0, stream, query, Wc, qp);
    hipLaunchKernelGGL(score_kernel,   dim3(4096),  dim3(256), 0, stream, enc, We, qp, V, sp);
    hipLaunchKernelGGL(softmax_kernel, dim3(NB),    dim3(256), 0, stream, sp, mask, wts);
    hipLaunchKernelGGL(context_kernel, dim3(256),   dim3(256), 0, stream, enc, wts, ctx);
}

// Round 4
// 358.935 us; speedup vs baseline: 1.7819x; 1.0923x over previous
//
#include <hip/hip_runtime.h>
#include <hip/hip_bf16.h>

#define NB 32
#define NS 2048
#define NDD 1024
#define NDE 1024
#define NDA 1024
#define NEGV (-1000000000.0f)

typedef __attribute__((ext_vector_type(8))) __bf16 bf16x8;
typedef __attribute__((ext_vector_type(4))) float f32x4;

__device__ __forceinline__ float fast_tanh(float x) {
    x = fminf(10.0f, fmaxf(-10.0f, x));
    float e = __expf(2.0f * x);
    return __fdividef(e - 1.0f, e + 1.0f);
}

// ---------------- We (f32) -> bf16 conversion ----------------
__global__ void prep_we(const float* __restrict__ Wc, __bf16* __restrict__ We) {
    int f = blockIdx.x * 256 + threadIdx.x;
    int a  = f >> 8;
    int k4 = f & 255;
    float4 v = *reinterpret_cast<const float4*>(Wc + (size_t)a * (NDD + NDE) + NDD + k4 * 4);
    union { __bf16 h[4]; uint2 u; } pk;
    pk.h[0] = (__bf16)v.x; pk.h[1] = (__bf16)v.y;
    pk.h[2] = (__bf16)v.z; pk.h[3] = (__bf16)v.w;
    *reinterpret_cast<uint2*>(We + (size_t)a * NDE + k4 * 4) = pk.u;
}

// ---------------- q_proj = query @ Wq^T (f32, exact) ----------------
__global__ void qproj_kernel(const float* __restrict__ q, const float* __restrict__ Wc,
                             float* __restrict__ qp) {
    __shared__ float qs[NDD];
    int b = blockIdx.y;
    int a = blockIdx.x * 256 + threadIdx.x;
    float4 qv = *reinterpret_cast<const float4*>(q + (size_t)b * NDD + threadIdx.x * 4);
    *reinterpret_cast<float4*>(qs + threadIdx.x * 4) = qv;
    __syncthreads();
    const float* wrow = Wc + (size_t)a * (NDD + NDE);
    float acc = 0.f;
#pragma unroll 4
    for (int k4 = 0; k4 < 256; ++k4) {
        float4 w = *reinterpret_cast<const float4*>(wrow + k4 * 4);
        acc += qs[k4*4+0] * w.x + qs[k4*4+1] * w.y + qs[k4*4+2] * w.z + qs[k4*4+3] * w.w;
    }
    qp[(size_t)b * NDA + a] = acc;
}

// ---------------- fused e_proj GEMM + tanh + V-dot -> partial scores ----------------
// m97 geometry: 128x128 tile, BK=32, 256 thr / 4 waves (2x2), double-buffered bf16 LDS.
// A: reg-staged (f32 load -> cvt -> ds_write_b64, once per element). B: global_load_lds w16.
// Both tiles [128][32] bf16, slot swizzle: slot ^= (r>>1)&3  (2-way banks = free).
__global__ __launch_bounds__(256, 4) void score_kernel(
    const float* __restrict__ E, const __bf16* __restrict__ We,
    const float* __restrict__ qp, const float* __restrict__ Vv,
    float* __restrict__ scores_p) {
    __shared__ __align__(16) __bf16 As[2][128 * 32];   // 8 KB each
    __shared__ __align__(16) __bf16 Bs[2][128 * 32];   // 8 KB each
    __shared__ float ps_lds[128][2];

    const int tid    = threadIdx.x;
    const int lane   = tid & 63;
    const int lane15 = lane & 15;
    const int h      = lane >> 4;          // k-quarter 0..3
    const int wid    = tid >> 6;
    const int wr     = wid >> 1;
    const int wc     = wid & 1;

    // XCD-chunked swizzle: xcd gets a contiguous m-range, n fastest.
    const int bid = blockIdx.x;
    const int xcd = bid & 7;
    const int j   = bid >> 3;
    const int m   = xcd * 64 + (j >> 3);   // 0..511
    const int n   = j & 7;                 // 0..7
    const int row0  = m * 128;
    const int ncol0 = n * 128;
    const int b     = m >> 4;

    f32x4 acc[4][4];
#pragma unroll
    for (int mi = 0; mi < 4; ++mi)
#pragma unroll
        for (int ni = 0; ni < 4; ++ni)
            acc[mi][ni] = (f32x4){0.f, 0.f, 0.f, 0.f};

    const int wbyte = wid * 1024;          // wave-uniform LDS sub-base for global_load_lds

    float4 st[4];                          // in-flight A tile (reg-staged)

#define A_LOAD(kc)                                                                     \
    {                                                                                  \
        _Pragma("unroll")                                                              \
        for (int i = 0; i < 4; ++i)                                                    \
            st[i] = *reinterpret_cast<const float4*>(                                  \
                E + (size_t)(row0 + i * 32 + (tid >> 3)) * NDE + (kc) + (tid & 7) * 4);\
    }

#define A_WRITE(buf)                                                                   \
    {                                                                                  \
        _Pragma("unroll")                                                              \
        for (int i = 0; i < 4; ++i) {                                                  \
            int r  = i * 32 + (tid >> 3);                                              \
            int sl = ((tid & 7) >> 1) ^ ((r >> 1) & 3);                                \
            union { __bf16 hh[4]; uint2 u; } pk;                                       \
            pk.hh[0] = (__bf16)st[i].x; pk.hh[1] = (__bf16)st[i].y;                    \
            pk.hh[2] = (__bf16)st[i].z; pk.hh[3] = (__bf16)st[i].w;                    \
            *reinterpret_cast<uint2*>((char*)&As[buf][0] + r * 64 + sl * 16 + (tid & 1) * 8) = pk.u; \
        }                                                                              \
    }

#define B_STAGE(buf, kc)                                                               \
    {                                                                                  \
        _Pragma("unroll")                                                              \
        for (int i = 0; i < 2; ++i) {                                                  \
            int ib = i * 4096 + tid * 16;                                              \
            int r  = ib >> 6;                                                          \
            int sl = (ib >> 4) & 3;                                                    \
            int sg = sl ^ ((r >> 1) & 3);                                              \
            const __bf16* g = We + (size_t)(ncol0 + r) * NDE + (kc) + sg * 8;          \
            __builtin_amdgcn_global_load_lds(                                          \
                (const __attribute__((address_space(1))) unsigned*)g,                  \
                (__attribute__((address_space(3))) unsigned*)((char*)&Bs[buf][0] + i * 4096 + wbyte), \
                16, 0, 0);                                                             \
        }                                                                              \
    }

    // prologue: stage tile 0
    A_LOAD(0)
    B_STAGE(0, 0)
    A_WRITE(0)
    __syncthreads();

    for (int it = 0; it < 32; ++it) {
        const int cur = it & 1;
        if (it < 31) {
            A_LOAD((it + 1) * 32)
            B_STAGE(cur ^ 1, (it + 1) * 32)
        }
        const char* Ab = (const char*)&As[cur][0];
        const char* Bb = (const char*)&Bs[cur][0];
        bf16x8 bfr[4], afr[4];
#pragma unroll
        for (int ni = 0; ni < 4; ++ni) {
            int cr = wc * 64 + ni * 16 + lane15;
            bfr[ni] = *reinterpret_cast<const bf16x8*>(Bb + cr * 64 + ((h ^ ((cr >> 1) & 3)) * 16));
        }
#pragma unroll
        for (int mi = 0; mi < 4; ++mi) {
            int r = wr * 64 + mi * 16 + lane15;
            afr[mi] = *reinterpret_cast<const bf16x8*>(Ab + r * 64 + ((h ^ ((r >> 1) & 3)) * 16));
        }
#pragma unroll
        for (int mi = 0; mi < 4; ++mi)
#pragma unroll
            for (int ni = 0; ni < 4; ++ni)
                acc[mi][ni] = __builtin_amdgcn_mfma_f32_16x16x32_bf16(afr[mi], bfr[ni], acc[mi][ni], 0, 0, 0);
        if (it < 31) A_WRITE(cur ^ 1)
        __syncthreads();
    }

    // ---- epilogue: tanh(qp + e_proj) * V, reduce over cols ----
    float qv[4], vv[4];
#pragma unroll
    for (int ni = 0; ni < 4; ++ni) {
        int col = ncol0 + wc * 64 + ni * 16 + lane15;
        qv[ni] = qp[(size_t)b * NDA + col];
        vv[ni] = Vv[col];
    }
#pragma unroll
    for (int mi = 0; mi < 4; ++mi)
#pragma unroll
        for (int jj = 0; jj < 4; ++jj) {
            float s = 0.f;
#pragma unroll
            for (int ni = 0; ni < 4; ++ni)
                s += fast_tanh(qv[ni] + acc[mi][ni][jj]) * vv[ni];
            s += __shfl_xor(s, 1);
            s += __shfl_xor(s, 2);
            s += __shfl_xor(s, 4);
            s += __shfl_xor(s, 8);
            if (lane15 == 0)
                ps_lds[wr * 64 + mi * 16 + h * 4 + jj][wc] = s;
        }
    __syncthreads();
    if (tid < 128)
        scores_p[(size_t)n * (NB * NS) + row0 + tid] = ps_lds[tid][0] + ps_lds[tid][1];
}

// ---------------- masked softmax over s (sums 8 partials), per b ----------------
__global__ void softmax_kernel(const float* __restrict__ sp, const int* __restrict__ mask,
                               float* __restrict__ wout) {
    int b = blockIdx.x;
    const int* mrow = mask + (size_t)b * NS;
    float v[8];
    float lmax = -INFINITY;
#pragma unroll
    for (int jj = 0; jj < 8; ++jj) {
        int s = threadIdx.x + 256 * jj;
        float sc = 0.f;
#pragma unroll
        for (int nn = 0; nn < 8; ++nn) sc += sp[(size_t)nn * (NB * NS) + b * NS + s];
        v[jj] = (mrow[s] == 0) ? NEGV : sc;
        lmax = fmaxf(lmax, v[jj]);
    }
#pragma unroll
    for (int mm = 1; mm <= 32; mm <<= 1) lmax = fmaxf(lmax, __shfl_xor(lmax, mm));
    __shared__ float redm[4], reds[4];
    if ((threadIdx.x & 63) == 0) redm[threadIdx.x >> 6] = lmax;
    __syncthreads();
    float bmax = fmaxf(fmaxf(redm[0], redm[1]), fmaxf(redm[2], redm[3]));
    float lsum = 0.f;
#pragma unroll
    for (int jj = 0; jj < 8; ++jj) { v[jj] = __expf(v[jj] - bmax); lsum += v[jj]; }
#pragma unroll
    for (int mm = 1; mm <= 32; mm <<= 1) lsum += __shfl_xor(lsum, mm);
    if ((threadIdx.x & 63) == 0) reds[threadIdx.x >> 6] = lsum;
    __syncthreads();
    float inv = __fdividef(1.0f, reds[0] + reds[1] + reds[2] + reds[3]);
#pragma unroll
    for (int jj = 0; jj < 8; ++jj) wout[(size_t)b * NS + threadIdx.x + 256 * jj] = v[jj] * inv;
}

// ---------------- context = w @ E ----------------
__global__ void context_kernel(const float* __restrict__ E, const float* __restrict__ w,
                               float* __restrict__ ctx) {
    int b  = blockIdx.x >> 3;
    int dc = blockIdx.x & 7;
    int d2 = dc * 64 + (threadIdx.x & 63);
    int s0 = (threadIdx.x >> 6) * 512;
    const float2* Eb = reinterpret_cast<const float2*>(E) + (size_t)b * NS * (NDE / 2);
    const float* wb = w + (size_t)b * NS;
    float ax = 0.f, ay = 0.f;
#pragma unroll 8
    for (int s = s0; s < s0 + 512; ++s) {
        float ws = wb[s];
        float2 e = Eb[(size_t)s * (NDE / 2) + d2];
        ax = fmaf(ws, e.x, ax);
        ay = fmaf(ws, e.y, ay);
    }
    __shared__ float2 part[256];
    part[threadIdx.x] = make_float2(ax, ay);
    __syncthreads();
    if (threadIdx.x < 64) {
        float2 p0 = part[threadIdx.x], p1 = part[threadIdx.x + 64];
        float2 p2 = part[threadIdx.x + 128], p3 = part[threadIdx.x + 192];
        float2 r = make_float2(p0.x + p1.x + p2.x + p3.x, p0.y + p1.y + p2.y + p3.y);
        reinterpret_cast<float2*>(ctx + (size_t)b * NDD + dc * 128)[threadIdx.x] = r;
    }
}

extern "C" void kernel_launch(void* const* d_in, const int* in_sizes, int n_in,
                              void* d_out, int out_size, void* d_ws, size_t ws_size,
                              hipStream_t stream) {
    const float* query = (const float*)d_in[0];
    const float* enc   = (const float*)d_in[1];
    const int*   mask  = (const int*)d_in[2];
    const float* Wc    = (const float*)d_in[3];
    const float* V     = (const float*)d_in[4];

    float* out = (float*)d_out;
    float* ctx = out;                       // (32,1024)
    float* wts = out + NB * NDD;            // (32,2048)

    char* ws = (char*)d_ws;
    __bf16* We     = (__bf16*)ws;                                          // 2 MB
    float*  qp     = (float*)(ws + (size_t)NDA * NDE * 2);                 // 128 KB
    float*  sp     = (float*)(ws + (size_t)NDA * NDE * 2 + NB * NDA * 4);  // 2 MB (8 partials)

    hipLaunchKernelGGL(prep_we,        dim3(1024),  dim3(256), 0, stream, Wc, We);
    hipLaunchKernelGGL(qproj_kernel,   dim3(4, NB), dim3(256), 0, stream, query, Wc, qp);
    hipLaunchKernelGGL(score_kernel,   dim3(4096),  dim3(256), 0, stream, enc, We, qp, V, sp);
    hipLaunchKernelGGL(softmax_kernel, dim3(NB),    dim3(256), 0, stream, sp, mask, wts);
    hipLaunchKernelGGL(context_kernel, dim3(256),   dim3(256), 0, stream, enc, wts, ctx);
}